// Round 2
// baseline (284.615 us; speedup 1.0000x reference)
//
#include <hip/hip_runtime.h>
#include <hip/hip_bf16.h>

// CapsuleLayer dynamic routing, B=512, P=1152, N=10, T=16, D=8, 3 iters.
// All buffers fp32 (values are bf16-rounded upstream; harness compares with
// a bf16-floor threshold). b_ij update is mean-over-batch with keepdims ->
// b_ij and the coupling c are batch-independent (P,N). pred (378 MB) is
// never materialized; recomputed in each of 5 passes (3x s, 2x agreement).

constexpr int B_ = 512;
constexpr int P_ = 1152;
constexpr int N_ = 10;
constexpr int T_ = 16;
constexpr int D_ = 8;
constexpr int NT_ = N_ * T_;   // 160
constexpr int PT_ = 18;        // p per k_s block (1152/18 = 64 tiles)
constexpr int LDW_ = 12;       // LDS row stride (floats): 12 -> worst 2-way bank conflict (free)

// s[b,n,t] = sum_p c[p,n] * (sum_d W[p,n,t,d] * x[b,p,d])
// grid (8, 64): 64-b tile x 18-p tile. 256 threads: (bg=tid>>4, col=tid&15)
// owns 4 consecutive b and t=col for all 10 n. Atomic-accumulate into s.
__global__ __launch_bounds__(256) void k_s(const float* __restrict__ x,
                                           const float* __restrict__ W,
                                           const float* __restrict__ c,
                                           float* __restrict__ s) {
    __shared__ __align__(16) float Ws[NT_ * LDW_];   // 160 rows
    __shared__ __align__(16) float xs[64 * LDW_];    // 64 rows
    __shared__ float cs[PT_ * N_];
    const int tid = threadIdx.x;
    const int col = tid & 15;
    const int bg  = tid >> 4;
    const int b0 = blockIdx.x * 64;
    const int p0 = blockIdx.y * PT_;

    if (tid < PT_ * N_) cs[tid] = c[p0 * N_ + tid];

    float acc[N_][4];
#pragma unroll
    for (int n = 0; n < N_; ++n)
#pragma unroll
        for (int j = 0; j < 4; ++j) acc[n][j] = 0.f;

    for (int pp = 0; pp < PT_; ++pp) {
        const int p = p0 + pp;
        __syncthreads();
        if (tid < NT_) {
            const float* g = W + ((size_t)p * NT_ + tid) * D_;
            *(float4*)&Ws[tid * LDW_]     = *(const float4*)g;
            *(float4*)&Ws[tid * LDW_ + 4] = *(const float4*)(g + 4);
        } else if (tid < NT_ + 64) {
            const int r = tid - NT_;
            const float* g = x + ((size_t)(b0 + r) * P_ + p) * D_;
            *(float4*)&xs[r * LDW_]     = *(const float4*)g;
            *(float4*)&xs[r * LDW_ + 4] = *(const float4*)(g + 4);
        }
        __syncthreads();

        float xr[4][D_];
#pragma unroll
        for (int j = 0; j < 4; ++j) {
            float4 a = *(float4*)&xs[(bg * 4 + j) * LDW_];
            float4 b = *(float4*)&xs[(bg * 4 + j) * LDW_ + 4];
            xr[j][0] = a.x; xr[j][1] = a.y; xr[j][2] = a.z; xr[j][3] = a.w;
            xr[j][4] = b.x; xr[j][5] = b.y; xr[j][6] = b.z; xr[j][7] = b.w;
        }
#pragma unroll
        for (int n = 0; n < N_; ++n) {
            float4 wa = *(float4*)&Ws[(n * 16 + col) * LDW_];
            float4 wb = *(float4*)&Ws[(n * 16 + col) * LDW_ + 4];
            const float cn = cs[pp * N_ + n];
#pragma unroll
            for (int j = 0; j < 4; ++j) {
                float pred = wa.x * xr[j][0];
                pred = fmaf(wa.y, xr[j][1], pred);
                pred = fmaf(wa.z, xr[j][2], pred);
                pred = fmaf(wa.w, xr[j][3], pred);
                pred = fmaf(wb.x, xr[j][4], pred);
                pred = fmaf(wb.y, xr[j][5], pred);
                pred = fmaf(wb.z, xr[j][6], pred);
                pred = fmaf(wb.w, xr[j][7], pred);
                acc[n][j] = fmaf(cn, pred, acc[n][j]);
            }
        }
    }
#pragma unroll
    for (int n = 0; n < N_; ++n)
#pragma unroll
        for (int j = 0; j < 4; ++j)
            atomicAdd(&s[(size_t)(b0 + bg * 4 + j) * NT_ + n * 16 + col], acc[n][j]);
}

// squash per (b,n) row of 16 t's; final iteration writes fp32 output
__global__ __launch_bounds__(256) void k_v(const float* __restrict__ s,
                                           float* __restrict__ v) {
    const int i = blockIdx.x * blockDim.x + threadIdx.x;
    if (i >= B_ * N_) return;
    const float* sr = s + (size_t)i * T_;
    float sv[T_];
    float sq = 0.f;
#pragma unroll
    for (int t = 0; t < T_; ++t) { sv[t] = sr[t]; sq = fmaf(sv[t], sv[t], sq); }
    const float norm = sqrtf(sq);
    const float scale = sq / (1.0f + sq * (norm + 1e-9f));
#pragma unroll
    for (int t = 0; t < T_; ++t) v[(size_t)i * T_ + t] = sv[t] * scale;
}

// bbar[p,n] += (1/B) * sum_{b,t} (sum_d W[p,n,t,d] x[b,p,d]) * v[b,n,t]
// grid (144, 4): 8-p tile x 128-b chunk. thread (pl=tid>>5, r=tid&31) keeps
// W rows nt = r+32k (k=0..4) in registers across the whole b-loop.
__global__ __launch_bounds__(256) void k_a(const float* __restrict__ x,
                                           const float* __restrict__ W,
                                           const float* __restrict__ v,
                                           float* __restrict__ bbar) {
    __shared__ __align__(16) float vs[4 * NT_];     // 4 b x 160
    __shared__ __align__(16) float xs[4 * 8 * D_];  // 4 b x 8 p x 8
    const int tid = threadIdx.x;
    const int pl = tid >> 5;   // 0..7
    const int r  = tid & 31;
    const int p0 = blockIdx.x * 8;
    const int b0 = blockIdx.y * 128;

    float wreg[5][D_];
#pragma unroll
    for (int k = 0; k < 5; ++k) {
        const float* g = W + ((size_t)(p0 + pl) * NT_ + (r + 32 * k)) * D_;
        float4 a = *(const float4*)g;
        float4 b = *(const float4*)(g + 4);
        wreg[k][0] = a.x; wreg[k][1] = a.y; wreg[k][2] = a.z; wreg[k][3] = a.w;
        wreg[k][4] = b.x; wreg[k][5] = b.y; wreg[k][6] = b.z; wreg[k][7] = b.w;
    }
    float acc[5] = {0.f, 0.f, 0.f, 0.f, 0.f};

    for (int ci = 0; ci < 32; ++ci) {
        const int bc = b0 + ci * 4;
        __syncthreads();
        if (tid < 160) {
            const int bb = tid / 40, idx = tid % 40;
            *(float4*)&vs[bb * NT_ + idx * 4] =
                *(const float4*)&v[(size_t)(bc + bb) * NT_ + idx * 4];
        } else if (tid < 160 + 32) {
            const int r2 = tid - 160;
            const int bb = r2 >> 3, pp = r2 & 7;
            const float* g = x + ((size_t)(bc + bb) * P_ + p0 + pp) * D_;
            *(float4*)&xs[(bb * 8 + pp) * D_]     = *(const float4*)g;
            *(float4*)&xs[(bb * 8 + pp) * D_ + 4] = *(const float4*)(g + 4);
        }
        __syncthreads();
#pragma unroll
        for (int bb = 0; bb < 4; ++bb) {
            float4 a  = *(float4*)&xs[(bb * 8 + pl) * D_];
            float4 b2 = *(float4*)&xs[(bb * 8 + pl) * D_ + 4];
            const float xv[D_] = {a.x, a.y, a.z, a.w, b2.x, b2.y, b2.z, b2.w};
#pragma unroll
            for (int k = 0; k < 5; ++k) {
                float pred = wreg[k][0] * xv[0];
                pred = fmaf(wreg[k][1], xv[1], pred);
                pred = fmaf(wreg[k][2], xv[2], pred);
                pred = fmaf(wreg[k][3], xv[3], pred);
                pred = fmaf(wreg[k][4], xv[4], pred);
                pred = fmaf(wreg[k][5], xv[5], pred);
                pred = fmaf(wreg[k][6], xv[6], pred);
                pred = fmaf(wreg[k][7], xv[7], pred);
                acc[k] = fmaf(pred, vs[bb * NT_ + r + 32 * k], acc[k]);
            }
        }
    }
    // reduce over t = low 4 bits of lane id
#pragma unroll
    for (int off = 1; off < 16; off <<= 1) {
#pragma unroll
        for (int k = 0; k < 5; ++k) acc[k] += __shfl_xor(acc[k], off);
    }
    if ((tid & 15) == 0) {
#pragma unroll
        for (int k = 0; k < 5; ++k) {
            const int n = ((tid >> 4) & 1) + 2 * k;
            atomicAdd(&bbar[(size_t)(p0 + pl) * N_ + n], acc[k] * (1.0f / 512.0f));
        }
    }
}

// softmax over n (10) per p row
__global__ __launch_bounds__(256) void k_c(const float* __restrict__ bbar,
                                           float* __restrict__ c) {
    const int p = blockIdx.x * blockDim.x + threadIdx.x;
    if (p >= P_) return;
    float b[N_];
    float m = -1e30f;
#pragma unroll
    for (int n = 0; n < N_; ++n) { b[n] = bbar[p * N_ + n]; m = fmaxf(m, b[n]); }
    float sum = 0.f;
#pragma unroll
    for (int n = 0; n < N_; ++n) { b[n] = expf(b[n] - m); sum += b[n]; }
    const float inv = 1.f / sum;
#pragma unroll
    for (int n = 0; n < N_; ++n) c[p * N_ + n] = b[n] * inv;
}

extern "C" void kernel_launch(void* const* d_in, const int* in_sizes, int n_in,
                              void* d_out, int out_size, void* d_ws, size_t ws_size,
                              hipStream_t stream) {
    const float* x = (const float*)d_in[0];  // fp32 [B,P,D]
    const float* W = (const float*)d_in[1];  // fp32 [P,N,T,D]

    float* bbar = (float*)d_ws;          // P*N   = 11520
    float* c    = bbar + P_ * N_;        // 11520
    float* s    = c + P_ * N_;           // B*NT  = 81920
    float* v    = s + B_ * NT_;          // 81920   (total 747.5 KB)

    hipMemsetAsync(bbar, 0, (size_t)P_ * N_ * sizeof(float), stream);

    for (int it = 0; it < 3; ++it) {
        k_c<<<dim3((P_ + 255) / 256), dim3(256), 0, stream>>>(bbar, c);
        hipMemsetAsync(s, 0, (size_t)B_ * NT_ * sizeof(float), stream);
        k_s<<<dim3(8, 64), dim3(256), 0, stream>>>(x, W, c, s);
        if (it < 2) {
            k_v<<<dim3((B_ * N_ + 255) / 256), dim3(256), 0, stream>>>(s, v);
            k_a<<<dim3(144, 4), dim3(256), 0, stream>>>(x, W, v, bbar);
        } else {
            k_v<<<dim3((B_ * N_ + 255) / 256), dim3(256), 0, stream>>>(s, (float*)d_out);
        }
    }
}